// Round 2
// baseline (232.331 us; speedup 1.0000x reference)
//
#include <hip/hip_runtime.h>
#include <math.h>

#define LSEQ  512
#define BT    128
#define INF   512
#define HH    60
#define NSTEP 1536   // 3*LSEQ
#define CH2   6      // steps per lane in scan kernel: 1536 / 256

#define MTILE 128    // rows per block (k_phi); wave owns 32 rows
#define KSTG  128    // K extent staged in LDS per stage (4 stages of 128)
#define BROW  136    // LDS B row stride in bf16 (128 + 8 pad -> 2-way banks, free)

typedef __attribute__((ext_vector_type(8))) short bf16x8;
typedef __attribute__((ext_vector_type(4))) float floatx4;
typedef __attribute__((ext_vector_type(4))) unsigned short ushortx4;

// ---------- bf16 split helpers ---------------------------------------------
__device__ __forceinline__ unsigned short bf16_rn(float x) {
  unsigned u = __float_as_uint(x);
  return (unsigned short)((u + 0x7FFFu + ((u >> 16) & 1u)) >> 16);
}
__device__ __forceinline__ void split2(float x, unsigned short& h, unsigned short& l) {
  h = bf16_rn(x);
  float hf = __uint_as_float(((unsigned)h) << 16);
  l = bf16_rn(x - hf);
}

// ---------- kernel 1: split-bf16 MFMA GEMM + softmax + torsion angles ------
// W split fp32->(h,l) bf16 in-block during LDS staging (W is L2-resident).
// K staged in 4 chunks of 128 -> LDS 34.8 KB -> 4 blocks/CU (4 waves/SIMD),
// doubling TLP vs the previous 2-half/67.6KB version whose 1-step-deep A
// prefetch left ~280 cyc/step of exposed HBM latency at 2 waves/SIMD.
// K-loop within a stage is BARRIER-FREE; only global stream is A.
// acc += Ah*Bh + Ah*Bl + Al*Bh  (split-fp32, ~2^-17 relative).
__global__ __launch_bounds__(256, 4) void k_phi(
    const float* __restrict__ inp, const float* __restrict__ W,
    const float* __restrict__ bias, const float* __restrict__ alphabet,
    float* __restrict__ phi_out) {
  __shared__ unsigned short BhL[64 * BROW];   // 17408 B
  __shared__ unsigned short BlL[64 * BROW];   // 17408 B
  __shared__ float sS[HH * 3], sC[HH * 3], sBias[64];

  const int tid  = threadIdx.x;
  const int lane = tid & 63;
  const int wid  = tid >> 6;
  const int c    = lane & 15;        // frag row/col index
  const int quad = lane >> 4;        // 0..3
  const int row0 = blockIdx.x * MTILE;

  if (tid < HH * 3) { float a = alphabet[tid]; sS[tid] = __sinf(a); sC[tid] = __cosf(a); }
  if (tid >= 192 && tid < 256) { int n = tid - 192; sBias[n] = (n < HH) ? bias[n] : 0.f; }

  floatx4 acc[2][4];
#pragma unroll
  for (int mt = 0; mt < 2; ++mt)
#pragma unroll
    for (int nt = 0; nt < 4; ++nt) acc[mt][nt] = (floatx4){0.f, 0.f, 0.f, 0.f};

  // per-lane A row bases (m-tile mt row = wid*32 + 16*mt + c), k-offset quad*8
  const float* ap0 = inp + (size_t)(row0 + wid * 32 + c)      * INF + quad * 8;
  const float* ap1 = ap0 + 16 * INF;

  for (int stg = 0; stg < 4; ++stg) {
    const int kbase = stg * KSTG;
    if (stg) __syncthreads();           // all waves done reading previous stage
    // ---- stage B chunk: split W fp32 -> (Bh, Bl) bf16 64 x 128 in LDS ----
    // 2048 float4-chunks / 256 threads = 8 per thread; wave-coalesced.
#pragma unroll
    for (int i = 0; i < 8; ++i) {
      const int chunk = i * 256 + tid;  // 0..2047, 4 floats each
      const int r  = chunk >> 5;        // 0..63
      const int j4 = (chunk & 31) * 4;  // col 0..124 step 4
      float4 wv = make_float4(0.f, 0.f, 0.f, 0.f);
      if (r < HH) wv = *(const float4*)(W + (size_t)r * INF + kbase + j4);
      ushortx4 hv, lv;
      unsigned short hb, lb;
      split2(wv.x, hb, lb); hv[0] = hb; lv[0] = lb;
      split2(wv.y, hb, lb); hv[1] = hb; lv[1] = lb;
      split2(wv.z, hb, lb); hv[2] = hb; lv[2] = lb;
      split2(wv.w, hb, lb); hv[3] = hb; lv[3] = lb;
      *(ushortx4*)&BhL[r * BROW + j4] = hv;
      *(ushortx4*)&BlL[r * BROW + j4] = lv;
    }
    __syncthreads();

    // ---- prefetch A for step 0 of this stage ----
    float4 pa0, pa1, pa2, pa3;
    pa0 = *(const float4*)(ap0 + kbase);
    pa1 = *(const float4*)(ap0 + kbase + 4);
    pa2 = *(const float4*)(ap1 + kbase);
    pa3 = *(const float4*)(ap1 + kbase + 4);

#pragma unroll
    for (int ks = 0; ks < 4; ++ks) {    // K=32 per step, barrier-free
      const int kl = ks * 32;           // k within stage
      float4 a00 = pa0, a01 = pa1, a10 = pa2, a11 = pa3;
      if (ks + 1 < 4) {                 // issue next step's A loads now
        pa0 = *(const float4*)(ap0 + kbase + kl + 32);
        pa1 = *(const float4*)(ap0 + kbase + kl + 36);
        pa2 = *(const float4*)(ap1 + kbase + kl + 32);
        pa3 = *(const float4*)(ap1 + kbase + kl + 36);
      }
      // ---- B fragments from LDS (2-way banks = free) ----
      bf16x8 Bh[4], Bl[4];
#pragma unroll
      for (int nt = 0; nt < 4; ++nt) {
        const int boff = (nt * 16 + c) * BROW + kl + quad * 8;
        Bh[nt] = *(const bf16x8*)&BhL[boff];
        Bl[nt] = *(const bf16x8*)&BlL[boff];
      }
      // ---- split A to bf16 h/l fragments in registers ----
      bf16x8 Ah[2], Al[2];
      {
        float av[2][8] = {{a00.x,a00.y,a00.z,a00.w,a01.x,a01.y,a01.z,a01.w},
                          {a10.x,a10.y,a10.z,a10.w,a11.x,a11.y,a11.z,a11.w}};
#pragma unroll
        for (int mt = 0; mt < 2; ++mt)
#pragma unroll
          for (int j = 0; j < 8; ++j) {
            unsigned short hb, lb; split2(av[mt][j], hb, lb);
            Ah[mt][j] = (short)hb; Al[mt][j] = (short)lb;
          }
      }
#pragma unroll
      for (int mt = 0; mt < 2; ++mt)
#pragma unroll
        for (int nt = 0; nt < 4; ++nt) {
          acc[mt][nt] = __builtin_amdgcn_mfma_f32_16x16x32_bf16(Ah[mt], Bh[nt], acc[mt][nt], 0, 0, 0);
          acc[mt][nt] = __builtin_amdgcn_mfma_f32_16x16x32_bf16(Ah[mt], Bl[nt], acc[mt][nt], 0, 0, 0);
          acc[mt][nt] = __builtin_amdgcn_mfma_f32_16x16x32_bf16(Al[mt], Bh[nt], acc[mt][nt], 0, 0, 0);
        }
    }
  }

  // ---- epilogue: C/D layout row = quad*4+reg, col = lane&15 ----
#pragma unroll
  for (int mt = 0; mt < 2; ++mt) {
#pragma unroll
    for (int reg = 0; reg < 4; ++reg) {
      float lg[4];  bool val[4];
#pragma unroll
      for (int nt = 0; nt < 4; ++nt) {
        const int n = nt * 16 + c;
        val[nt] = (n < HH);
        lg[nt] = acc[mt][nt][reg] + sBias[n];
      }
      float m = -1e30f;
#pragma unroll
      for (int nt = 0; nt < 4; ++nt) if (val[nt]) m = fmaxf(m, lg[nt]);
#pragma unroll
      for (int d = 1; d < 16; d <<= 1) m = fmaxf(m, __shfl_xor(m, d, 64));

      float s0=0.f,c0=0.f,s1=0.f,c1=0.f,s2=0.f,c2=0.f;
#pragma unroll
      for (int nt = 0; nt < 4; ++nt) {
        const int n = nt * 16 + c;
        float e = val[nt] ? __expf(lg[nt] - m) : 0.f;
        s0 = fmaf(e, sS[n*3+0], s0);  c0 = fmaf(e, sC[n*3+0], c0);
        s1 = fmaf(e, sS[n*3+1], s1);  c1 = fmaf(e, sC[n*3+1], c1);
        s2 = fmaf(e, sS[n*3+2], s2);  c2 = fmaf(e, sC[n*3+2], c2);
      }
#pragma unroll
      for (int d = 1; d < 16; d <<= 1) {
        s0 += __shfl_xor(s0, d, 64);  c0 += __shfl_xor(c0, d, 64);
        s1 += __shfl_xor(s1, d, 64);  c1 += __shfl_xor(c1, d, 64);
        s2 += __shfl_xor(s2, d, 64);  c2 += __shfl_xor(c2, d, 64);
      }
      if (c == 0) {
        const int row = row0 + wid * 32 + mt * 16 + quad * 4 + reg;
        const int l  = row >> 7;        // / BT
        const int bb = row & 127;       // % BT
        float* pp = phi_out + (size_t)bb * NSTEP + 3 * l;
        pp[0] = atan2f(s0, c0);
        pp[1] = atan2f(s1, c1);
        pp[2] = atan2f(s2, c2);
      }
    }
  }
}

// ---------- rigid transform (3x3 rotation row-major + translation) ----------
struct Xf { float r[9]; float p[3]; };

__device__ __forceinline__ Xf compose(const Xf& A, const Xf& B) {
  Xf o;
#pragma unroll
  for (int i = 0; i < 3; ++i) {
#pragma unroll
    for (int j = 0; j < 3; ++j) {
      o.r[i*3+j] = fmaf(A.r[i*3+0], B.r[0+j],
                   fmaf(A.r[i*3+1], B.r[3+j],
                        A.r[i*3+2] * B.r[6+j]));
    }
    o.p[i] = fmaf(A.r[i*3+0], B.p[0],
             fmaf(A.r[i*3+1], B.p[1],
             fmaf(A.r[i*3+2], B.p[2], A.p[i])));
  }
  return o;
}

__device__ __forceinline__ Xf make_T(float phi, float st, float ct, float r) {
  float sp = __sinf(phi), cp = __cosf(phi);
  Xf T;
  T.r[0] = ct;      T.r[1] = -st;     T.r[2] = 0.f;
  T.r[3] = cp * st; T.r[4] = ct * cp; T.r[5] = -sp;
  T.r[6] = sp * st; T.r[7] = ct * sp; T.r[8] = cp;
  T.p[0] = r * ct;  T.p[1] = r * T.r[3]; T.p[2] = r * T.r[6];
  return T;
}

__device__ __forceinline__ void set_identity(Xf& X) {
  X.r[0]=1.f; X.r[1]=0.f; X.r[2]=0.f;
  X.r[3]=0.f; X.r[4]=1.f; X.r[5]=0.f;
  X.r[6]=0.f; X.r[7]=0.f; X.r[8]=1.f;
  X.p[0]=0.f; X.p[1]=0.f; X.p[2]=0.f;
}

// ---------- kernel 2: two-level parallel rigid-transform scan ---------------
__global__ __launch_bounds__(256) void k_scan(
    const float* __restrict__ phi, const float* __restrict__ bl,
    const float* __restrict__ ba, float* __restrict__ out) {
  __shared__ Xf wt[4];

  const int b = blockIdx.x;       // chain 0..127
  const int t = threadIdx.x & 63; // lane in wave
  const int w = threadIdx.x >> 6; // wave 0..3
  const int g = threadIdx.x;      // global lane 0..255

  float st[3], ct[3], rr[3];
#pragma unroll
  for (int j = 0; j < 3; ++j) {
    float a = ba[j];
    st[j] = __sinf(a); ct[j] = __cosf(a); rr[j] = bl[j];
  }

  // steps for this lane: g*6 .. g*6+5 ; (g*6+s)%3 == s%3 since 6%3==0
  float f[CH2];
  const float2* ph2 = (const float2*)(phi + (size_t)b * NSTEP + g * CH2);
#pragma unroll
  for (int q = 0; q < CH2/2; ++q) {
    float2 v = ph2[q];
    f[2*q+0] = v.x; f[2*q+1] = v.y;
  }

  Xf Q = make_T(f[0], st[0], ct[0], rr[0]);
#pragma unroll
  for (int s = 1; s < CH2; ++s)
    Q = compose(Q, make_T(f[s], st[s%3], ct[s%3], rr[s%3]));

  // wave-level inclusive scan (left-compose earlier lanes)
#pragma unroll
  for (int d = 1; d < 64; d <<= 1) {
    Xf O;
#pragma unroll
    for (int q = 0; q < 9; ++q) O.r[q] = __shfl_up(Q.r[q], d, 64);
#pragma unroll
    for (int q = 0; q < 3; ++q) O.p[q] = __shfl_up(Q.p[q], d, 64);
    if (t < d) set_identity(O);
    Q = compose(O, Q);
  }

  // cross-wave totals
  if (t == 63) wt[w] = Q;
  __syncthreads();

  // wave-local exclusive prefix
  Xf E;
#pragma unroll
  for (int q = 0; q < 9; ++q) E.r[q] = __shfl_up(Q.r[q], 1, 64);
#pragma unroll
  for (int q = 0; q < 3; ++q) E.p[q] = __shfl_up(Q.p[q], 1, 64);
  if (t == 0) set_identity(E);

  Xf S0;
  S0.r[0] = 0.f;                  S0.r[1] = 0.816496580927726f;   S0.r[2] = 0.5773502691896258f;
  S0.r[3] = -0.7071067811865475f; S0.r[4] = -0.4082482904638631f; S0.r[5] = 0.5773502691896258f;
  S0.r[6] = 0.7071067811865475f;  S0.r[7] = -0.4082482904638631f; S0.r[8] = 0.5773502691896258f;
  S0.p[0] = 0.f; S0.p[1] = 0.f; S0.p[2] = 1.f;

  // SP = S0 ∘ (wt[0] ∘ ... ∘ wt[w-1])  (wave-uniform, <=3 composes)
  Xf SP = S0;
#pragma unroll
  for (int i = 0; i < 3; ++i)
    if (i < w) SP = compose(SP, wt[i]);

  Xf cur = compose(SP, E);

  float* op = out + (size_t)(g * CH2) * (BT * 3) + b * 3;
#pragma unroll
  for (int s = 0; s < CH2; ++s) {
    cur = compose(cur, make_T(f[s], st[s%3], ct[s%3], rr[s%3]));
    op[(size_t)s * (BT*3) + 0] = cur.p[0];
    op[(size_t)s * (BT*3) + 1] = cur.p[1];
    op[(size_t)s * (BT*3) + 2] = cur.p[2];
  }
}

// ---------- launch ---------------------------------------------------------
extern "C" void kernel_launch(void* const* d_in, const int* in_sizes, int n_in,
                              void* d_out, int out_size, void* d_ws, size_t ws_size,
                              hipStream_t stream) {
  const float* inp      = (const float*)d_in[0];
  const float* W        = (const float*)d_in[1];
  const float* bias     = (const float*)d_in[2];
  const float* alphabet = (const float*)d_in[3];
  const float* bl       = (const float*)d_in[4];
  const float* ba       = (const float*)d_in[5];
  float* out = (float*)d_out;

  float* phi = (float*)d_ws;   // 786432 B

  k_phi<<<dim3((LSEQ*BT)/MTILE), dim3(256), 0, stream>>>(inp, W, bias, alphabet, phi);
  k_scan<<<dim3(BT), dim3(256), 0, stream>>>(phi, bl, ba, out);
}

// Round 3
// 221.287 us; speedup vs baseline: 1.0499x; 1.0499x over previous
//
#include <hip/hip_runtime.h>
#include <math.h>

#define LSEQ  512
#define BT    128
#define INF   512
#define HH    60
#define NSTEP 1536   // 3*LSEQ
#define CH2   6      // steps per lane in scan kernel: 1536 / 256

#define MTILE 64     // rows per block (k_phi); wave owns 16 rows
#define KSTG  128    // K extent staged in LDS per stage (4 stages of 128)
#define BROW  136    // LDS B row stride in bf16 (128 + 8 pad)

typedef __attribute__((ext_vector_type(8))) short bf16x8;
typedef __attribute__((ext_vector_type(4))) float floatx4;
typedef __attribute__((ext_vector_type(4))) unsigned short ushortx4;

// ---------- bf16 split helpers ---------------------------------------------
__device__ __forceinline__ unsigned short bf16_rn(float x) {
  unsigned u = __float_as_uint(x);
  return (unsigned short)((u + 0x7FFFu + ((u >> 16) & 1u)) >> 16);
}
__device__ __forceinline__ void split2(float x, unsigned short& h, unsigned short& l) {
  h = bf16_rn(x);
  float hf = __uint_as_float(((unsigned)h) << 16);
  l = bf16_rn(x - hf);
}

// ---------- kernel 1: split-bf16 MFMA GEMM + softmax + torsion angles ------
// MTILE=64 -> grid 1024 -> 4 blocks/CU resident (LDS 36 KB), 16 waves/CU.
// Per-wave live set ~70 VGPR (acc in AGPRs) -> no spill at the 128-VGPR cap.
// A prefetch is SEAMLESS across stage boundaries: next A loads issue before
// the staging barriers (A addressing doesn't depend on LDS), so the only
// exposed HBM latency is the very first step of the kernel.
// acc += Ah*Bh + Ah*Bl + Al*Bh  (split-fp32, ~2^-17 relative).
__global__ __launch_bounds__(256, 4) void k_phi(
    const float* __restrict__ inp, const float* __restrict__ W,
    const float* __restrict__ bias, const float* __restrict__ alphabet,
    float* __restrict__ phi_out) {
  __shared__ unsigned short BhL[64 * BROW];   // 17408 B
  __shared__ unsigned short BlL[64 * BROW];   // 17408 B
  __shared__ float sS[HH * 3], sC[HH * 3], sBias[64];

  const int tid  = threadIdx.x;
  const int lane = tid & 63;
  const int wid  = tid >> 6;
  const int c    = lane & 15;        // frag row/col index
  const int quad = lane >> 4;        // 0..3
  const int row0 = blockIdx.x * MTILE;

  if (tid < HH * 3) { float a = alphabet[tid]; sS[tid] = __sinf(a); sC[tid] = __cosf(a); }
  if (tid >= 192 && tid < 256) { int n = tid - 192; sBias[n] = (n < HH) ? bias[n] : 0.f; }

  floatx4 acc[4];
#pragma unroll
  for (int nt = 0; nt < 4; ++nt) acc[nt] = (floatx4){0.f, 0.f, 0.f, 0.f};

  // per-lane A row base (wave owns rows wid*16 .. wid*16+15), k-offset quad*8
  const float* ap0 = inp + (size_t)(row0 + wid * 16 + c) * INF + quad * 8;

  // ---- initial A prefetch (k = 0) ----
  float4 pa0 = *(const float4*)(ap0);
  float4 pa1 = *(const float4*)(ap0 + 4);

  for (int stg = 0; stg < 4; ++stg) {
    const int kbase = stg * KSTG;
    if (stg) __syncthreads();           // all waves done reading previous stage
    // ---- stage B chunk: split W fp32 -> (Bh, Bl) bf16 64 x 128 in LDS ----
#pragma unroll
    for (int i = 0; i < 8; ++i) {
      const int chunk = i * 256 + tid;  // 0..2047, 4 floats each
      const int r  = chunk >> 5;        // 0..63
      const int j4 = (chunk & 31) * 4;  // col 0..124 step 4
      float4 wv = make_float4(0.f, 0.f, 0.f, 0.f);
      if (r < HH) wv = *(const float4*)(W + (size_t)r * INF + kbase + j4);
      ushortx4 hv, lv;
      unsigned short hb, lb;
      split2(wv.x, hb, lb); hv[0] = hb; lv[0] = lb;
      split2(wv.y, hb, lb); hv[1] = hb; lv[1] = lb;
      split2(wv.z, hb, lb); hv[2] = hb; lv[2] = lb;
      split2(wv.w, hb, lb); hv[3] = hb; lv[3] = lb;
      *(ushortx4*)&BhL[r * BROW + j4] = hv;
      *(ushortx4*)&BlL[r * BROW + j4] = lv;
    }
    __syncthreads();

#pragma unroll
    for (int ks = 0; ks < 4; ++ks) {    // K=32 per step, barrier-free
      const int kl = ks * 32;           // k within stage
      const int kg = kbase + kl;        // global k
      float4 a00 = pa0, a01 = pa1;
      if (kg + 32 < INF) {              // seamless prefetch (crosses stages)
        pa0 = *(const float4*)(ap0 + kg + 32);
        pa1 = *(const float4*)(ap0 + kg + 36);
      }
      // ---- B fragments from LDS ----
      bf16x8 Bh[4], Bl[4];
#pragma unroll
      for (int nt = 0; nt < 4; ++nt) {
        const int boff = (nt * 16 + c) * BROW + kl + quad * 8;
        Bh[nt] = *(const bf16x8*)&BhL[boff];
        Bl[nt] = *(const bf16x8*)&BlL[boff];
      }
      // ---- split A to bf16 h/l fragments in registers ----
      bf16x8 Ah, Al;
      {
        float av[8] = {a00.x,a00.y,a00.z,a00.w,a01.x,a01.y,a01.z,a01.w};
#pragma unroll
        for (int j = 0; j < 8; ++j) {
          unsigned short hb, lb; split2(av[j], hb, lb);
          Ah[j] = (short)hb; Al[j] = (short)lb;
        }
      }
#pragma unroll
      for (int nt = 0; nt < 4; ++nt) {
        acc[nt] = __builtin_amdgcn_mfma_f32_16x16x32_bf16(Ah, Bh[nt], acc[nt], 0, 0, 0);
        acc[nt] = __builtin_amdgcn_mfma_f32_16x16x32_bf16(Ah, Bl[nt], acc[nt], 0, 0, 0);
        acc[nt] = __builtin_amdgcn_mfma_f32_16x16x32_bf16(Al, Bh[nt], acc[nt], 0, 0, 0);
      }
    }
  }

  // ---- epilogue: C/D layout row = quad*4+reg, col = lane&15 ----
#pragma unroll
  for (int reg = 0; reg < 4; ++reg) {
    float lg[4];  bool val[4];
#pragma unroll
    for (int nt = 0; nt < 4; ++nt) {
      const int n = nt * 16 + c;
      val[nt] = (n < HH);
      lg[nt] = acc[nt][reg] + sBias[n];
    }
    float m = -1e30f;
#pragma unroll
    for (int nt = 0; nt < 4; ++nt) if (val[nt]) m = fmaxf(m, lg[nt]);
#pragma unroll
    for (int d = 1; d < 16; d <<= 1) m = fmaxf(m, __shfl_xor(m, d, 64));

    float s0=0.f,c0=0.f,s1=0.f,c1=0.f,s2=0.f,c2=0.f;
#pragma unroll
    for (int nt = 0; nt < 4; ++nt) {
      const int n = nt * 16 + c;
      float e = val[nt] ? __expf(lg[nt] - m) : 0.f;
      s0 = fmaf(e, sS[n*3+0], s0);  c0 = fmaf(e, sC[n*3+0], c0);
      s1 = fmaf(e, sS[n*3+1], s1);  c1 = fmaf(e, sC[n*3+1], c1);
      s2 = fmaf(e, sS[n*3+2], s2);  c2 = fmaf(e, sC[n*3+2], c2);
    }
#pragma unroll
    for (int d = 1; d < 16; d <<= 1) {
      s0 += __shfl_xor(s0, d, 64);  c0 += __shfl_xor(c0, d, 64);
      s1 += __shfl_xor(s1, d, 64);  c1 += __shfl_xor(c1, d, 64);
      s2 += __shfl_xor(s2, d, 64);  c2 += __shfl_xor(c2, d, 64);
    }
    if (c == 0) {
      const int row = row0 + wid * 16 + quad * 4 + reg;
      const int l  = row >> 7;        // / BT
      const int bb = row & 127;       // % BT
      float* pp = phi_out + (size_t)bb * NSTEP + 3 * l;
      pp[0] = atan2f(s0, c0);
      pp[1] = atan2f(s1, c1);
      pp[2] = atan2f(s2, c2);
    }
  }
}

// ---------- rigid transform (3x3 rotation row-major + translation) ----------
struct Xf { float r[9]; float p[3]; };

__device__ __forceinline__ Xf compose(const Xf& A, const Xf& B) {
  Xf o;
#pragma unroll
  for (int i = 0; i < 3; ++i) {
#pragma unroll
    for (int j = 0; j < 3; ++j) {
      o.r[i*3+j] = fmaf(A.r[i*3+0], B.r[0+j],
                   fmaf(A.r[i*3+1], B.r[3+j],
                        A.r[i*3+2] * B.r[6+j]));
    }
    o.p[i] = fmaf(A.r[i*3+0], B.p[0],
             fmaf(A.r[i*3+1], B.p[1],
             fmaf(A.r[i*3+2], B.p[2], A.p[i])));
  }
  return o;
}

__device__ __forceinline__ Xf make_T(float phi, float st, float ct, float r) {
  float sp = __sinf(phi), cp = __cosf(phi);
  Xf T;
  T.r[0] = ct;      T.r[1] = -st;     T.r[2] = 0.f;
  T.r[3] = cp * st; T.r[4] = ct * cp; T.r[5] = -sp;
  T.r[6] = sp * st; T.r[7] = ct * sp; T.r[8] = cp;
  T.p[0] = r * ct;  T.p[1] = r * T.r[3]; T.p[2] = r * T.r[6];
  return T;
}

__device__ __forceinline__ void set_identity(Xf& X) {
  X.r[0]=1.f; X.r[1]=0.f; X.r[2]=0.f;
  X.r[3]=0.f; X.r[4]=1.f; X.r[5]=0.f;
  X.r[6]=0.f; X.r[7]=0.f; X.r[8]=1.f;
  X.p[0]=0.f; X.p[1]=0.f; X.p[2]=0.f;
}

// ---------- kernel 2: two-level parallel rigid-transform scan ---------------
__global__ __launch_bounds__(256) void k_scan(
    const float* __restrict__ phi, const float* __restrict__ bl,
    const float* __restrict__ ba, float* __restrict__ out) {
  __shared__ Xf wt[4];

  const int b = blockIdx.x;       // chain 0..127
  const int t = threadIdx.x & 63; // lane in wave
  const int w = threadIdx.x >> 6; // wave 0..3
  const int g = threadIdx.x;      // global lane 0..255

  float st[3], ct[3], rr[3];
#pragma unroll
  for (int j = 0; j < 3; ++j) {
    float a = ba[j];
    st[j] = __sinf(a); ct[j] = __cosf(a); rr[j] = bl[j];
  }

  // steps for this lane: g*6 .. g*6+5 ; (g*6+s)%3 == s%3 since 6%3==0
  float f[CH2];
  const float2* ph2 = (const float2*)(phi + (size_t)b * NSTEP + g * CH2);
#pragma unroll
  for (int q = 0; q < CH2/2; ++q) {
    float2 v = ph2[q];
    f[2*q+0] = v.x; f[2*q+1] = v.y;
  }

  Xf Q = make_T(f[0], st[0], ct[0], rr[0]);
#pragma unroll
  for (int s = 1; s < CH2; ++s)
    Q = compose(Q, make_T(f[s], st[s%3], ct[s%3], rr[s%3]));

  // wave-level inclusive scan (left-compose earlier lanes)
#pragma unroll
  for (int d = 1; d < 64; d <<= 1) {
    Xf O;
#pragma unroll
    for (int q = 0; q < 9; ++q) O.r[q] = __shfl_up(Q.r[q], d, 64);
#pragma unroll
    for (int q = 0; q < 3; ++q) O.p[q] = __shfl_up(Q.p[q], d, 64);
    if (t < d) set_identity(O);
    Q = compose(O, Q);
  }

  // cross-wave totals
  if (t == 63) wt[w] = Q;
  __syncthreads();

  // wave-local exclusive prefix
  Xf E;
#pragma unroll
  for (int q = 0; q < 9; ++q) E.r[q] = __shfl_up(Q.r[q], 1, 64);
#pragma unroll
  for (int q = 0; q < 3; ++q) E.p[q] = __shfl_up(Q.p[q], 1, 64);
  if (t == 0) set_identity(E);

  Xf S0;
  S0.r[0] = 0.f;                  S0.r[1] = 0.816496580927726f;   S0.r[2] = 0.5773502691896258f;
  S0.r[3] = -0.7071067811865475f; S0.r[4] = -0.4082482904638631f; S0.r[5] = 0.5773502691896258f;
  S0.r[6] = 0.7071067811865475f;  S0.r[7] = -0.4082482904638631f; S0.r[8] = 0.5773502691896258f;
  S0.p[0] = 0.f; S0.p[1] = 0.f; S0.p[2] = 1.f;

  // SP = S0 ∘ (wt[0] ∘ ... ∘ wt[w-1])  (wave-uniform, <=3 composes)
  Xf SP = S0;
#pragma unroll
  for (int i = 0; i < 3; ++i)
    if (i < w) SP = compose(SP, wt[i]);

  Xf cur = compose(SP, E);

  float* op = out + (size_t)(g * CH2) * (BT * 3) + b * 3;
#pragma unroll
  for (int s = 0; s < CH2; ++s) {
    cur = compose(cur, make_T(f[s], st[s%3], ct[s%3], rr[s%3]));
    op[(size_t)s * (BT*3) + 0] = cur.p[0];
    op[(size_t)s * (BT*3) + 1] = cur.p[1];
    op[(size_t)s * (BT*3) + 2] = cur.p[2];
  }
}

// ---------- launch ---------------------------------------------------------
extern "C" void kernel_launch(void* const* d_in, const int* in_sizes, int n_in,
                              void* d_out, int out_size, void* d_ws, size_t ws_size,
                              hipStream_t stream) {
  const float* inp      = (const float*)d_in[0];
  const float* W        = (const float*)d_in[1];
  const float* bias     = (const float*)d_in[2];
  const float* alphabet = (const float*)d_in[3];
  const float* bl       = (const float*)d_in[4];
  const float* ba       = (const float*)d_in[5];
  float* out = (float*)d_out;

  float* phi = (float*)d_ws;   // 786432 B

  k_phi<<<dim3((LSEQ*BT)/MTILE), dim3(256), 0, stream>>>(inp, W, bias, alphabet, phi);
  k_scan<<<dim3(BT), dim3(256), 0, stream>>>(phi, bl, ba, out);
}